// Round 11
// baseline (205.510 us; speedup 1.0000x reference)
//
#include <hip/hip_runtime.h>
#include <math.h>

#define BB 4
#define NN 2048
#define MM 2048
#define HEADS 8
#define DH 64

typedef _Float16 f16;
typedef _Float16 f16x4 __attribute__((ext_vector_type(4)));
typedef _Float16 f16x8 __attribute__((ext_vector_type(8)));
typedef float f32x4 __attribute__((ext_vector_type(4)));
typedef unsigned short ushort;

#define LOG2E 1.44269504088896f
#define QSCALE (0.125f * LOG2E)

#if __has_builtin(__builtin_amdgcn_exp2f)
#define EXP2(x) __builtin_amdgcn_exp2f(x)
#else
#define EXP2(x) exp2f(x)
#endif

__device__ __forceinline__ f16x4 pk4(float a, float b, float c, float d) {
#if __has_builtin(__builtin_amdgcn_cvt_pkrtz)
    auto t0 = __builtin_amdgcn_cvt_pkrtz(a, b);
    auto t1 = __builtin_amdgcn_cvt_pkrtz(c, d);
    f16x4 r;
    r[0] = t0[0]; r[1] = t0[1]; r[2] = t1[0]; r[3] = t1[1];
    return r;
#else
    f16x4 r = {(f16)a, (f16)b, (f16)c, (f16)d};
    return r;
#endif
}

// async global->LDS, 16B per lane, dest = wave-uniform base + lane*16
__device__ __forceinline__ void gl16(const void* g, void* l) {
    __builtin_amdgcn_global_load_lds(
        (const __attribute__((address_space(1))) unsigned int*)g,
        (__attribute__((address_space(3))) unsigned int*)l, 16, 0, 0);
}

// RTE f32x8 -> f16x8 (matches the original (f16) cast path bit-for-bit)
__device__ __forceinline__ f16x8 cvt8(float4 lo, float4 hi) {
    f16x8 r;
    r[0] = (f16)lo.x; r[1] = (f16)lo.y; r[2] = (f16)lo.z; r[3] = (f16)lo.w;
    r[4] = (f16)hi.x; r[5] = (f16)hi.y; r[6] = (f16)hi.z; r[7] = (f16)hi.w;
    return r;
}

// ---------------------------------------------------------------------------
// Fused weight prep: Wq->[N][K]f16, Wkv->[N][K]f16, Wo->[N][K] f16 hi/lo.
// 512 blocks: [0,128) Wq, [128,384) Wkv, [384,512) Wo.  (frozen)
// ---------------------------------------------------------------------------
__global__ void wprep_k(const float* __restrict__ Wq, const float* __restrict__ Wkv,
                        const float* __restrict__ Wo,
                        f16* __restrict__ wq16, f16* __restrict__ wkv16,
                        f16* __restrict__ woh, f16* __restrict__ wol)
{
    __shared__ f16 S0[64 * 36], S1[64 * 36];
    const int tid = threadIdx.x;
    const int bid = blockIdx.x;
    const int K = 512;
    const float* W; int N; f16* T16; f16 *Th, *Tl; int id;
    if (bid < 128)      { W = Wq;  N = 512;  T16 = wq16;  Th = 0; Tl = 0; id = bid; }
    else if (bid < 384) { W = Wkv; N = 1024; T16 = wkv16; Th = 0; Tl = 0; id = bid - 128; }
    else                { W = Wo;  N = 512;  T16 = 0; Th = woh; Tl = wol; id = bid - 384; }
    const int k0 = (id & 15) * 32, n0 = (id >> 4) * 64;
    const int kr = tid >> 3, nc = (tid & 7) * 8;
    float4 v0 = *(const float4*)(W + (size_t)(k0 + kr) * N + n0 + nc);
    float4 v1 = *(const float4*)(W + (size_t)(k0 + kr) * N + n0 + nc + 4);
    float e[8] = {v0.x, v0.y, v0.z, v0.w, v1.x, v1.y, v1.z, v1.w};
    const int n = tid >> 2, kc = (tid & 3) * 8;
    if (T16) {
#pragma unroll
        for (int j = 0; j < 8; j++) S0[(nc + j) * 36 + kr] = (f16)e[j];
        __syncthreads();
        *(uint4*)(T16 + (size_t)(n0 + n) * K + k0 + kc) = *(const uint4*)(S0 + n * 36 + kc);
    } else {
#pragma unroll
        for (int j = 0; j < 8; j++) {
            f16 h = (f16)e[j];
            S0[(nc + j) * 36 + kr] = h;
            S1[(nc + j) * 36 + kr] = (f16)(e[j] - (float)h);
        }
        __syncthreads();
        *(uint4*)(Th + (size_t)(n0 + n) * K + k0 + kc) = *(const uint4*)(S0 + n * 36 + kc);
        *(uint4*)(Tl + (size_t)(n0 + n) * K + k0 + kc) = *(const uint4*)(S1 + n * 36 + kc);
    }
}

// ---------------------------------------------------------------------------
// Fused projections v5 (frozen from round 9): 4-buffer counted-vmcnt
// pipeline; A rows wave-private -> registers.
// ---------------------------------------------------------------------------
__launch_bounds__(256, 3)
__global__ void proj_k(const float* __restrict__ x, const float* __restrict__ ctx,
                       const f16* __restrict__ wq16, const f16* __restrict__ wkv16,
                       f16* __restrict__ qws, f16* __restrict__ kws, f16* __restrict__ vt)
{
    __shared__ __align__(16) char smem[32768];   // 4 x B:8KB

    const int tid  = threadIdx.x;
    const int wave = tid >> 6, lane = tid & 63;
    const int l15  = lane & 15, quad = lane >> 4;
    const int by = blockIdx.y;
    const int isQ = (by < 4);
    const float* A32 = isQ ? x : ctx;
    const f16* Bt  = isQ ? wq16 : wkv16;
    const int c0 = (isQ ? by : by - 4) * 128;
    const size_t r0 = (size_t)blockIdx.x * 128;
    const int K = 512;

    const int blr = lane >> 2;
    const int bsw = (lane & 3) ^ ((lane >> 3) & 3);
    const char* bP = (const char*)(Bt + (size_t)(c0 + wave * 32 + blr) * K) + bsw * 16;
    char* bD = smem + wave * 2048;               // + buf*8192 (+1024 for i=1)

    const float* aB0 = A32 + (r0 + wave * 32 + l15) * K + quad * 8;
    const float* aB1 = aB0 + 16 * K;
    float4 a0lo = *(const float4*)(aB0);
    float4 a0hi = *(const float4*)(aB0 + 4);
    float4 a1lo = *(const float4*)(aB1);
    float4 a1hi = *(const float4*)(aB1 + 4);
    int ak = 32;

    gl16(bP,          bD);
    gl16(bP + 16384,  bD + 1024);
    bP += 64;
    gl16(bP,          bD + 8192);
    gl16(bP + 16384,  bD + 8192 + 1024);
    bP += 64;
    gl16(bP,          bD + 16384);
    gl16(bP + 16384,  bD + 16384 + 1024);
    bP += 64;

    const int fsw = ((quad ^ ((l15 >> 1) & 3)) << 4);     // B read xor

    f32x4 acc[2][8] = {};

#pragma unroll
    for (int t = 0; t < 16; t++) {
        if (t == 0)       asm volatile("s_waitcnt vmcnt(0)"  ::: "memory");
        else if (t == 14) asm volatile("s_waitcnt vmcnt(10)" ::: "memory");
        else if (t == 15) asm volatile("s_waitcnt vmcnt(8)"  ::: "memory");
        else              asm volatile("s_waitcnt vmcnt(12)" ::: "memory");
        __builtin_amdgcn_s_barrier();

        f16x8 a[2];
        a[0] = cvt8(a0lo, a0hi);
        a[1] = cvt8(a1lo, a1hi);
        if (t < 15) {
            a0lo = *(const float4*)(aB0 + ak);
            a0hi = *(const float4*)(aB0 + ak + 4);
            a1lo = *(const float4*)(aB1 + ak);
            a1hi = *(const float4*)(aB1 + ak + 4);
            ak += 32;
        }
        if (t < 13) {
            char* nD = bD + (((t + 3) & 3) << 13);
            gl16(bP,          nD);
            gl16(bP + 16384,  nD + 1024);
            bP += 64;
        }

        const char* sB = smem + ((t & 3) << 13);
#pragma unroll
        for (int half = 0; half < 2; half++) {
            f16x8 b[4];
#pragma unroll
            for (int c = 0; c < 4; c++)
                b[c] = *(const f16x8*)(sB + ((half * 4 + c) * 16 + l15) * 64 + fsw);
#pragma unroll
            for (int rt = 0; rt < 2; rt++)
#pragma unroll
                for (int c = 0; c < 4; c++)
                    acc[rt][half * 4 + c] = __builtin_amdgcn_mfma_f32_16x16x32_f16(
                        a[rt], b[c], acc[rt][half * 4 + c], 0, 0, 0);
        }
    }

    const int b    = (int)(r0 >> 11);
    const int rloc = ((int)(r0 & 2047)) + wave * 32;

#pragma unroll
    for (int rt = 0; rt < 2; rt++)
#pragma unroll
        for (int ct = 0; ct < 8; ct++) {
            const int col = c0 + ct * 16 + l15;
            if (isQ || col < 512) {
                const int h = (col >> 6) & 7;
                const int d = col & 63;
                f16* dst = isQ ? qws : kws;
                const float sc = isQ ? QSCALE : 1.0f;
#pragma unroll
                for (int reg = 0; reg < 4; reg++) {
                    const int nn = rloc + rt * 16 + quad * 4 + reg;
                    dst[(((size_t)b * 8 + h) * 2048 + nn) * 64 + d] =
                        (f16)(tanhf(acc[rt][ct][reg]) * sc);
                }
            } else {
                const int c = col - 512;
                const int h = c >> 6;
                const int d = c & 63;
                const int m0 = rloc + rt * 16 + quad * 4;
                f16x4 pk;
#pragma unroll
                for (int reg = 0; reg < 4; reg++) pk[reg] = (f16)acc[rt][ct][reg];
                *(f16x4*)(vt + (((size_t)b * 8 + h) * 64 + d) * 2048 + m0) = pk;
            }
        }
}

// ---------------------------------------------------------------------------
// MFMA fp16 flash attention — INSTRUMENTATION ROUND: jh=2 partials launched
// as TWO separate dispatches (jh is a kernel ARG), each ~29us, so the top-5
// profile threshold drops below proj/mgemm and reveals whichever of them is
// the hidden time sink. Inner loop identical to the proven v9 core
// (round-7 jh=2 config measured 57.2us for both halves combined).
// ---------------------------------------------------------------------------
__launch_bounds__(256, 4)
__global__ void attn_k(const f16* __restrict__ qws, const f16* __restrict__ kws,
                       const f16* __restrict__ vtws,
                       const int* __restrict__ mask, const int* __restrict__ cmask,
                       const float* __restrict__ nk, const float* __restrict__ nv,
                       f16* __restrict__ Opf, float* __restrict__ lp, int jh)
{
    __shared__ __align__(16) char smem[32768];   // [2][ K:8192 | V:8192 ]

    const int tid  = threadIdx.x;
    const int wave = tid >> 6, lane = tid & 63;
    const int l15  = lane & 15, quad = lane >> 4;
    const int bh = blockIdx.x, b = bh >> 3, h = bh & 7;
    const int q0 = blockIdx.y * 128 + wave * 32;
    const int jbeg = jh << 10, jend = jbeg + 1024;

    const f16* kg0 = kws + (size_t)bh * MM * DH;
    const f16* vg0 = vtws + (size_t)bh * DH * MM;

    const int lrow = lane >> 3;
    const int lsw  = ((lane & 7) ^ lrow) << 4;
    const char* kP = (const char*)kg0 + (size_t)(jbeg + wave * 16 + lrow) * 128 + lsw;
    const char* vP = (const char*)vg0 + (size_t)(wave * 16 + lrow) * 4096
                   + (size_t)jbeg * 2 + lsw;
    char* kD = smem + wave * 2048;
    char* vD = smem + 8192 + wave * 2048;

    gl16(kP,         kD);
    gl16(kP + 1024,  kD + 1024);
    gl16(vP,         vD);
    gl16(vP + 32768, vD + 1024);
    kP += 8192; vP += 128;

    f16x8 qf[2][2];
    const f16* qbase = qws + ((size_t)bh * NN + q0) * DH;
#pragma unroll
    for (int rt = 0; rt < 2; rt++)
#pragma unroll
        for (int ks = 0; ks < 2; ks++)
            qf[rt][ks] = *(const f16x8*)(qbase + (rt * 16 + l15) * DH + ks * 32 + quad * 8);

    int rowOk[2];
#pragma unroll
    for (int rt = 0; rt < 2; rt++)
        rowOk[rt] = mask[(size_t)b * NN + q0 + rt * 16 + l15];

    float pnull[2] = {0.0f, 0.0f};
    if (jh == 0) {
        float pn[2] = {0.f, 0.f};
#pragma unroll
        for (int ks = 0; ks < 2; ks++)
#pragma unroll
            for (int t = 0; t < 8; t++) {
                const float nkt = tanhf(nk[ks * 32 + quad * 8 + t]);
                pn[0] += (float)qf[0][ks][t] * nkt;
                pn[1] += (float)qf[1][ks][t] * nkt;
            }
#pragma unroll
        for (int rt = 0; rt < 2; rt++) {
            pn[rt] += __shfl_xor(pn[rt], 16);
            pn[rt] += __shfl_xor(pn[rt], 32);
            pnull[rt] = rowOk[rt] ? EXP2(pn[rt]) : 1.0f;
        }
    }
    float negsel[2];
#pragma unroll
    for (int rt = 0; rt < 2; rt++) {
        negsel[rt] = rowOk[rt] ? -1.0e30f : 0.0f;
        if (!rowOk[rt]) {
            const f16x8 zz = {(f16)0, (f16)0, (f16)0, (f16)0, (f16)0, (f16)0, (f16)0, (f16)0};
            qf[rt][0] = zz; qf[rt][1] = zz;
        }
    }

    f32x4 acc[2][4];
    f32x4 accl[2];
#pragma unroll
    for (int rt = 0; rt < 2; rt++)
#pragma unroll
        for (int reg = 0; reg < 4; reg++) {
            const float pr = __shfl(pnull[rt], quad * 4 + reg, 16);
            accl[rt][reg] = pr;
#pragma unroll
            for (int ds = 0; ds < 4; ds++)
                acc[rt][ds][reg] = pr * nv[ds * 16 + l15];
        }

    const f16x4 vone = {(f16)1, (f16)1, (f16)1, (f16)1};
    const int kxor = l15 & 7;

    __syncthreads();

    int buf = 0;
    for (int jc = jbeg; jc < jend; jc += 64) {
        int4 cmv[4];
#pragma unroll
        for (int jj = 0; jj < 4; jj++)
            cmv[jj] = *(const int4*)(cmask + (size_t)b * MM + jc + jj * 16 + quad * 4);

        if (jc + 64 < jend) {
            const int bo = (buf ^ 1) << 14;
            gl16(kP,         kD + bo);
            gl16(kP + 1024,  kD + bo + 1024);
            gl16(vP,         vD + bo);
            gl16(vP + 32768, vD + bo + 1024);
            kP += 8192; vP += 128;
        }

        const char* sKb = smem + (buf << 14);
        const char* sVb = sKb + 8192;

        f32x4 st[2][4];
#pragma unroll
        for (int rt = 0; rt < 2; rt++)
#pragma unroll
            for (int jj = 0; jj < 4; jj++) {
                st[rt][jj][0] = cmv[jj].x ? 0.0f : negsel[rt];
                st[rt][jj][1] = cmv[jj].y ? 0.0f : negsel[rt];
                st[rt][jj][2] = cmv[jj].z ? 0.0f : negsel[rt];
                st[rt][jj][3] = cmv[jj].w ? 0.0f : negsel[rt];
            }

#pragma unroll
        for (int ks = 0; ks < 2; ks++) {
            f16x8 kb[4];
#pragma unroll
            for (int jj = 0; jj < 4; jj++)
                kb[jj] = *(const f16x8*)(sKb + (jj * 16 + l15) * 128
                                             + (((ks * 4 + quad) ^ kxor) << 4));
#pragma unroll
            for (int rt = 0; rt < 2; rt++)
#pragma unroll
                for (int jj = 0; jj < 4; jj++)
                    st[rt][jj] = __builtin_amdgcn_mfma_f32_16x16x32_f16(
                        kb[jj], qf[rt][ks], st[rt][jj], 0, 0, 0);
        }

        f16x4 pa[2][4];
#pragma unroll
        for (int rt = 0; rt < 2; rt++)
#pragma unroll
            for (int jj = 0; jj < 4; jj++)
                pa[rt][jj] = pk4(EXP2(st[rt][jj][0]), EXP2(st[rt][jj][1]),
                                 EXP2(st[rt][jj][2]), EXP2(st[rt][jj][3]));

#pragma unroll
        for (int jj = 0; jj < 4; jj++) {
            f16x4 vb[4];
#pragma unroll
            for (int ds = 0; ds < 4; ds++)
                vb[ds] = *(const f16x4*)(sVb + (ds * 16 + l15) * 128
                                             + (((jj * 2 + (quad >> 1)) ^ kxor) << 4)
                                             + ((quad & 1) << 3));
#pragma unroll
            for (int rt = 0; rt < 2; rt++) {
#pragma unroll
                for (int ds = 0; ds < 4; ds++)
                    acc[rt][ds] = __builtin_amdgcn_mfma_f32_16x16x16f16(
                        pa[rt][jj], vb[ds], acc[rt][ds], 0, 0, 0);
                accl[rt] = __builtin_amdgcn_mfma_f32_16x16x16f16(
                    pa[rt][jj], vone, accl[rt], 0, 0, 0);
            }
        }

        __syncthreads();
        buf ^= 1;
    }

    // epilogue: normalized f16 partials + l
#pragma unroll
    for (int rt = 0; rt < 2; rt++) {
        float inv[4];
#pragma unroll
        for (int reg = 0; reg < 4; reg++)
            inv[reg] = 1.0f / fmaxf(accl[rt][reg], 1e-35f);
#pragma unroll
        for (int ds = 0; ds < 4; ds++)
#pragma unroll
            for (int reg = 0; reg < 4; reg++) {
                const int r = q0 + rt * 16 + quad * 4 + reg;
                Opf[((size_t)jh * 8192 + b * 2048 + r) * 512 + h * 64 + ds * 16 + l15] =
                    (f16)(acc[rt][ds][reg] * inv[reg]);
            }
    }
    if (l15 == 0) {
#pragma unroll
        for (int rt = 0; rt < 2; rt++)
#pragma unroll
            for (int reg = 0; reg < 4; reg++)
                lp[((size_t)jh * 32 + bh) * 2048 + q0 + rt * 16 + quad * 4 + reg] =
                    accl[rt][reg];
    }
}

// ---------------------------------------------------------------------------
// Merge 2 j-partials: O = sum(Ohat_p * l_p) / sum(l_p) -> f16 of16.
// (round-7-proven code, verbatim)
// ---------------------------------------------------------------------------
__global__ void merge_k(const f16* __restrict__ Opf, const float* __restrict__ lp,
                        f16* __restrict__ of16)
{
    const int i = blockIdx.x * 256 + threadIdx.x;   // 1,048,576 threads
    const int row = i >> 7;                          // 0..8191
    const int c4  = i & 127;
    const int b = row >> 11, n = row & 2047, h = c4 >> 4;
    float w[2], den = 0.f;
#pragma unroll
    for (int jh = 0; jh < 2; jh++) {
        w[jh] = lp[((size_t)jh * 32 + b * 8 + h) * 2048 + n];
        den += w[jh];
    }
    const float inv = 1.0f / den;
    float v0 = 0, v1 = 0, v2 = 0, v3 = 0;
#pragma unroll
    for (int jh = 0; jh < 2; jh++) {
        f16x4 o = *(const f16x4*)(Opf + ((size_t)jh * 8192 + row) * 512 + c4 * 4);
        v0 += (float)o[0] * w[jh];
        v1 += (float)o[1] * w[jh];
        v2 += (float)o[2] * w[jh];
        v3 += (float)o[3] * w[jh];
    }
    f16x4 r = pk4(v0 * inv, v1 * inv, v2 * inv, v3 * inv);
    *(f16x4*)(of16 + (size_t)row * 512 + c4 * 4) = r;
}

// ---------------------------------------------------------------------------
// Final GEMM v3 (frozen): 128x64 tiles, grid (64,8) = 2 blocks/CU, gl16 DMA
// staging of A+Bh+Bl into linear dbuf LDS 2x16KB, one barrier per k-step.
// ---------------------------------------------------------------------------
__launch_bounds__(256, 4)
__global__ void mgemm2(const f16* __restrict__ A, const f16* __restrict__ Bh,
                       const f16* __restrict__ Bl,
                       float* __restrict__ o32, const float* __restrict__ bias,
                       int K)
{
    __shared__ __align__(16) char smem[32768];   // 2 x [A:8KB | Bh:4KB | Bl:4KB]

    const int tid  = threadIdx.x;
    const int wave = tid >> 6, lane = tid & 63;
    const int l15  = lane & 15, quad = lane >> 4;
    const size_t r0 = (size_t)blockIdx.x * 128;
    const int c0 = blockIdx.y * 64;

    const int blr = lane >> 2;
    const int bsw = (lane & 3) ^ ((lane >> 3) & 3);
    const char* aP = (const char*)(A + (r0 + wave * 32 + blr) * K) + bsw * 16;
    const char* hP = (const char*)(Bh + (size_t)(c0 + wave * 16 + blr) * K) + bsw * 16;
    const char* lP = (const char*)(Bl + (size_t)(c0 + wave * 16 + blr) * K) + bsw * 16;
    char* aD = smem + wave * 2048;
    char* hD = smem + 8192 + wave * 1024;
    char* lD = smem + 12288 + wave * 1024;

    gl16(aP,          aD);
    gl16(aP + 16384,  aD + 1024);   // +16 rows (16*512*2 B)
    gl16(hP,          hD);
    gl16(lP,          lD);
    aP += 64; hP += 64; lP += 64;

    const int fsw = ((quad ^ ((l15 >> 1) & 3)) << 4);
    const int aoff0 = (wave * 32 + l15) * 64 + fsw;
    const int aoff1 = aoff0 + 16 * 64;

    f32x4 acc[2][4] = {};
    __syncthreads();

    int buf = 0;
    const int NT = K / 32;
    for (int t = 0; t < NT; t++) {
        const int nb = (buf ^ 1) * 16384;
        if (t < NT - 1) {
            gl16(aP,          aD + nb);
            gl16(aP + 16384,  aD + nb + 1024);
            gl16(hP,          hD + nb);
            gl16(lP,          lD + nb);
            aP += 64; hP += 64; lP += 64;
        }
        const char* sA = smem + buf * 16384;
        const char* sH = sA + 8192;
        const char* sL = sA + 12288;

        f16x8 a[2];
        a[0] = *(const f16x8*)(sA + aoff0);
        a[1] = *(const f16x8*)(sA + aoff1);
#pragma unroll
        for (int ct = 0; ct < 4; ct++) {
            const int boff = (ct * 16 + l15) * 64 + fsw;
            f16x8 bh = *(const f16x8*)(sH + boff);
            f16x8 bl = *(const f16x8*)(sL + boff);
#pragma unroll
            for (int rt = 0; rt < 2; rt++) {
                acc[rt][ct] = __builtin_amdgcn_mfma_f32_16x16x32_f16(
                    a[rt], bh, acc[rt][ct], 0, 0, 0);
                acc[rt][ct] = __builtin_amdgcn_mfma_f32_16x16x32_f16(
                    a[rt], bl, acc[rt][ct], 0, 0, 0);
            }
        }
        __syncthreads();
        buf ^= 1;
    }

#pragma unroll
    for (int rt = 0; rt < 2; rt++)
#pragma unroll
        for (int ct = 0; ct < 4; ct++) {
            const int col = c0 + ct * 16 + l15;
            const float bv = bias[col];
#pragma unroll
            for (int reg = 0; reg < 4; reg++) {
                const size_t row = r0 + wave * 32 + rt * 16 + quad * 4 + reg;
                o32[row * 512 + col] = acc[rt][ct][reg] + bv;
            }
        }
}

extern "C" void kernel_launch(void* const* d_in, const int* in_sizes, int n_in,
                              void* d_out, int out_size, void* d_ws, size_t ws_size,
                              hipStream_t stream)
{
    const float* x    = (const float*)d_in[0];
    const float* ctx  = (const float*)d_in[1];
    const int*   mask = (const int*)d_in[2];
    const int*   cmsk = (const int*)d_in[3];
    const float* Wq   = (const float*)d_in[4];
    const float* Wkv  = (const float*)d_in[5];
    const float* Wo   = (const float*)d_in[6];
    const float* bo   = (const float*)d_in[7];
    const float* nk   = (const float*)d_in[8];
    const float* nv   = (const float*)d_in[9];
    float* out = (float*)d_out;

    const size_t S = (size_t)BB * HEADS * NN * DH;  // 4,194,304 elems

    f16* qws = (f16*)d_ws;                  // 8 MB
    f16* kws = qws + S;                     // 8 MB
    f16* vt  = kws + S;                     // 8 MB
    f16* wq16  = vt + S;                    // 0.5 MB
    f16* wkv16 = wq16 + 512 * 512;          // 1 MB
    f16* woh = wkv16 + 512 * 1024;          // 0.5 MB
    f16* wol = woh + 512 * 512;             // 0.5 MB
    float* lp = (float*)(wol + 512 * 512);  // 1 MB
    f16* Opf = (f16*)(lp + 4 * 32 * 2048);  // 32 MB (16 MB used, jh=2)
    f16* of16 = qws;                        // alias (qws dead after attn_k)

    wprep_k<<<512, 256, 0, stream>>>(Wq, Wkv, Wo, wq16, wkv16, woh, wol);
    proj_k<<<dim3(64, 12), 256, 0, stream>>>(x, ctx, wq16, wkv16, qws, kws, vt);
    attn_k<<<dim3(32, 16), 256, 0, stream>>>(qws, kws, vt, mask, cmsk, nk, nv, Opf, lp, 0);
    attn_k<<<dim3(32, 16), 256, 0, stream>>>(qws, kws, vt, mask, cmsk, nk, nv, Opf, lp, 1);
    merge_k<<<4096, 256, 0, stream>>>(Opf, lp, of16);
    mgemm2<<<dim3(64, 8), 256, 0, stream>>>(of16, woh, wol, out, bo, 512);
}

// Round 12
// 189.188 us; speedup vs baseline: 1.0863x; 1.0863x over previous
//
#include <hip/hip_runtime.h>
#include <math.h>

#define BB 4
#define NN 2048
#define MM 2048
#define HEADS 8
#define DH 64

typedef _Float16 f16;
typedef _Float16 f16x4 __attribute__((ext_vector_type(4)));
typedef _Float16 f16x8 __attribute__((ext_vector_type(8)));
typedef float f32x4 __attribute__((ext_vector_type(4)));
typedef unsigned short ushort;

#define LOG2E 1.44269504088896f
#define QSCALE (0.125f * LOG2E)

#if __has_builtin(__builtin_amdgcn_exp2f)
#define EXP2(x) __builtin_amdgcn_exp2f(x)
#else
#define EXP2(x) exp2f(x)
#endif

// tanh(x) = 1 - 2/(exp2(2x*log2e)+1); rcp(inf)=0 -> saturates to +/-1.
// err ~1e-6 << f16 quantization (5e-4). ~8 VALU ops vs libm's ~25.
__device__ __forceinline__ float fast_tanh(float v) {
    float e = EXP2(v * (2.0f * LOG2E));
    return 1.0f - 2.0f * __builtin_amdgcn_rcpf(e + 1.0f);
}

__device__ __forceinline__ f16x4 pk4(float a, float b, float c, float d) {
#if __has_builtin(__builtin_amdgcn_cvt_pkrtz)
    auto t0 = __builtin_amdgcn_cvt_pkrtz(a, b);
    auto t1 = __builtin_amdgcn_cvt_pkrtz(c, d);
    f16x4 r;
    r[0] = t0[0]; r[1] = t0[1]; r[2] = t1[0]; r[3] = t1[1];
    return r;
#else
    f16x4 r = {(f16)a, (f16)b, (f16)c, (f16)d};
    return r;
#endif
}

// async global->LDS, 16B per lane, dest = wave-uniform base + lane*16
__device__ __forceinline__ void gl16(const void* g, void* l) {
    __builtin_amdgcn_global_load_lds(
        (const __attribute__((address_space(1))) unsigned int*)g,
        (__attribute__((address_space(3))) unsigned int*)l, 16, 0, 0);
}

// RTE f32x8 -> f16x8 (matches the original (f16) cast path bit-for-bit)
__device__ __forceinline__ f16x8 cvt8(float4 lo, float4 hi) {
    f16x8 r;
    r[0] = (f16)lo.x; r[1] = (f16)lo.y; r[2] = (f16)lo.z; r[3] = (f16)lo.w;
    r[4] = (f16)hi.x; r[5] = (f16)hi.y; r[6] = (f16)hi.z; r[7] = (f16)hi.w;
    return r;
}

// ---------------------------------------------------------------------------
// Fused weight prep: Wq->[N][K]f16, Wkv->[N][K]f16, Wo->[N][K] f16 hi/lo.
// 512 blocks: [0,128) Wq, [128,384) Wkv, [384,512) Wo.  (frozen)
// ---------------------------------------------------------------------------
__global__ void wprep_k(const float* __restrict__ Wq, const float* __restrict__ Wkv,
                        const float* __restrict__ Wo,
                        f16* __restrict__ wq16, f16* __restrict__ wkv16,
                        f16* __restrict__ woh, f16* __restrict__ wol)
{
    __shared__ f16 S0[64 * 36], S1[64 * 36];
    const int tid = threadIdx.x;
    const int bid = blockIdx.x;
    const int K = 512;
    const float* W; int N; f16* T16; f16 *Th, *Tl; int id;
    if (bid < 128)      { W = Wq;  N = 512;  T16 = wq16;  Th = 0; Tl = 0; id = bid; }
    else if (bid < 384) { W = Wkv; N = 1024; T16 = wkv16; Th = 0; Tl = 0; id = bid - 128; }
    else                { W = Wo;  N = 512;  T16 = 0; Th = woh; Tl = wol; id = bid - 384; }
    const int k0 = (id & 15) * 32, n0 = (id >> 4) * 64;
    const int kr = tid >> 3, nc = (tid & 7) * 8;
    float4 v0 = *(const float4*)(W + (size_t)(k0 + kr) * N + n0 + nc);
    float4 v1 = *(const float4*)(W + (size_t)(k0 + kr) * N + n0 + nc + 4);
    float e[8] = {v0.x, v0.y, v0.z, v0.w, v1.x, v1.y, v1.z, v1.w};
    const int n = tid >> 2, kc = (tid & 3) * 8;
    if (T16) {
#pragma unroll
        for (int j = 0; j < 8; j++) S0[(nc + j) * 36 + kr] = (f16)e[j];
        __syncthreads();
        *(uint4*)(T16 + (size_t)(n0 + n) * K + k0 + kc) = *(const uint4*)(S0 + n * 36 + kc);
    } else {
#pragma unroll
        for (int j = 0; j < 8; j++) {
            f16 h = (f16)e[j];
            S0[(nc + j) * 36 + kr] = h;
            S1[(nc + j) * 36 + kr] = (f16)(e[j] - (float)h);
        }
        __syncthreads();
        *(uint4*)(Th + (size_t)(n0 + n) * K + k0 + kc) = *(const uint4*)(S0 + n * 36 + kc);
        *(uint4*)(Tl + (size_t)(n0 + n) * K + k0 + kc) = *(const uint4*)(S1 + n * 36 + kc);
    }
}

// ---------------------------------------------------------------------------
// Fused projections v6: v5's counted-vmcnt B pipeline + A prefetch DEPTH 2
// (A(t+2) issued at step t -> ~2 compute phases of cover for the HBM/L2
// latency the compiler-inserted wait before cvt8 was eating) + fast_tanh
// epilogue (64 calls/thread; libm tanh ~25 ops -> ~8).
// vmcnt ladder re-derived worst-case-safe under within-region reordering:
//   t=0 -> 0, t=1 -> 6, t=2..13 -> 12, t=14 -> 10, t=15 -> 4.
// (DMA(t) in region t-3; after it, regions t-2,t-1 hold A4+DMA2 each = 12.)
// ---------------------------------------------------------------------------
__launch_bounds__(256, 3)
__global__ void proj_k(const float* __restrict__ x, const float* __restrict__ ctx,
                       const f16* __restrict__ wq16, const f16* __restrict__ wkv16,
                       f16* __restrict__ qws, f16* __restrict__ kws, f16* __restrict__ vt)
{
    __shared__ __align__(16) char smem[32768];   // 4 x B:8KB

    const int tid  = threadIdx.x;
    const int wave = tid >> 6, lane = tid & 63;
    const int l15  = lane & 15, quad = lane >> 4;
    const int by = blockIdx.y;
    const int isQ = (by < 4);
    const float* A32 = isQ ? x : ctx;
    const f16* Bt  = isQ ? wq16 : wkv16;
    const int c0 = (isQ ? by : by - 4) * 128;
    const size_t r0 = (size_t)blockIdx.x * 128;
    const int K = 512;

    const int blr = lane >> 2;
    const int bsw = (lane & 3) ^ ((lane >> 3) & 3);
    const char* bP = (const char*)(Bt + (size_t)(c0 + wave * 32 + blr) * K) + bsw * 16;
    char* bD = smem + wave * 2048;               // + buf*8192 (+1024 for i=1)

    const float* aB0 = A32 + (r0 + wave * 32 + l15) * K + quad * 8;
    const float* aB1 = aB0 + 16 * K;

    // A depth-2 double buffer: aA[p][0,1]=rt0 lo/hi, aA[p][2,3]=rt1 lo/hi
    float4 aA[2][4];
    aA[0][0] = *(const float4*)(aB0);
    aA[0][1] = *(const float4*)(aB0 + 4);
    aA[0][2] = *(const float4*)(aB1);
    aA[0][3] = *(const float4*)(aB1 + 4);
    aA[1][0] = *(const float4*)(aB0 + 32);
    aA[1][1] = *(const float4*)(aB0 + 36);
    aA[1][2] = *(const float4*)(aB1 + 32);
    aA[1][3] = *(const float4*)(aB1 + 36);
    int ak = 64;

    // B DMA prologue: DMA(0),(1),(2) into bufs 0,1,2
    gl16(bP,          bD);
    gl16(bP + 16384,  bD + 1024);
    bP += 64;
    gl16(bP,          bD + 8192);
    gl16(bP + 16384,  bD + 8192 + 1024);
    bP += 64;
    gl16(bP,          bD + 16384);
    gl16(bP + 16384,  bD + 16384 + 1024);
    bP += 64;

    const int fsw = ((quad ^ ((l15 >> 1) & 3)) << 4);     // B read xor

    f32x4 acc[2][8] = {};

#pragma unroll
    for (int t = 0; t < 16; t++) {
        if (t == 0)       asm volatile("s_waitcnt vmcnt(0)"  ::: "memory");
        else if (t == 1)  asm volatile("s_waitcnt vmcnt(6)"  ::: "memory");
        else if (t == 14) asm volatile("s_waitcnt vmcnt(10)" ::: "memory");
        else if (t == 15) asm volatile("s_waitcnt vmcnt(4)"  ::: "memory");
        else              asm volatile("s_waitcnt vmcnt(12)" ::: "memory");
        __builtin_amdgcn_s_barrier();

        f16x8 a[2];
        a[0] = cvt8(aA[t & 1][0], aA[t & 1][1]);
        a[1] = cvt8(aA[t & 1][2], aA[t & 1][3]);
        if (t < 14) {                    // A(t+2): ~2 compute phases of cover
            aA[t & 1][0] = *(const float4*)(aB0 + ak);
            aA[t & 1][1] = *(const float4*)(aB0 + ak + 4);
            aA[t & 1][2] = *(const float4*)(aB1 + ak);
            aA[t & 1][3] = *(const float4*)(aB1 + ak + 4);
            ak += 32;
        }
        if (t < 13) {                    // DMA(t+3): ~3 phases of cover
            char* nD = bD + (((t + 3) & 3) << 13);
            gl16(bP,          nD);
            gl16(bP + 16384,  nD + 1024);
            bP += 64;
        }

        const char* sB = smem + ((t & 3) << 13);
#pragma unroll
        for (int half = 0; half < 2; half++) {
            f16x8 b[4];
#pragma unroll
            for (int c = 0; c < 4; c++)
                b[c] = *(const f16x8*)(sB + ((half * 4 + c) * 16 + l15) * 64 + fsw);
#pragma unroll
            for (int rt = 0; rt < 2; rt++)
#pragma unroll
                for (int c = 0; c < 4; c++)
                    acc[rt][half * 4 + c] = __builtin_amdgcn_mfma_f32_16x16x32_f16(
                        a[rt], b[c], acc[rt][half * 4 + c], 0, 0, 0);
        }
    }

    const int b    = (int)(r0 >> 11);
    const int rloc = ((int)(r0 & 2047)) + wave * 32;

#pragma unroll
    for (int rt = 0; rt < 2; rt++)
#pragma unroll
        for (int ct = 0; ct < 8; ct++) {
            const int col = c0 + ct * 16 + l15;
            if (isQ || col < 512) {
                const int h = (col >> 6) & 7;
                const int d = col & 63;
                f16* dst = isQ ? qws : kws;
                const float sc = isQ ? QSCALE : 1.0f;
#pragma unroll
                for (int reg = 0; reg < 4; reg++) {
                    const int nn = rloc + rt * 16 + quad * 4 + reg;
                    dst[(((size_t)b * 8 + h) * 2048 + nn) * 64 + d] =
                        (f16)(fast_tanh(acc[rt][ct][reg]) * sc);
                }
            } else {
                const int c = col - 512;
                const int h = c >> 6;
                const int d = c & 63;
                const int m0 = rloc + rt * 16 + quad * 4;
                f16x4 pk;
#pragma unroll
                for (int reg = 0; reg < 4; reg++) pk[reg] = (f16)acc[rt][ct][reg];
                *(f16x4*)(vt + (((size_t)b * 8 + h) * 64 + d) * 2048 + m0) = pk;
            }
        }
}

// ---------------------------------------------------------------------------
// MFMA fp16 flash attention v9 with jh=1 (round-8 config, frozen CONTROL):
// grid (32,16) = 512 blocks; each block walks ALL 2048 j (32 tiles); final
// normalized f16 output written directly (no partials/merge).
// ---------------------------------------------------------------------------
__launch_bounds__(256, 4)
__global__ void attn_k(const f16* __restrict__ qws, const f16* __restrict__ kws,
                       const f16* __restrict__ vtws,
                       const int* __restrict__ mask, const int* __restrict__ cmask,
                       const float* __restrict__ nk, const float* __restrict__ nv,
                       f16* __restrict__ ofx)
{
    __shared__ __align__(16) char smem[32768];   // [2][ K:8192 | V:8192 ]

    const int tid  = threadIdx.x;
    const int wave = tid >> 6, lane = tid & 63;
    const int l15  = lane & 15, quad = lane >> 4;
    const int bh = blockIdx.x, b = bh >> 3, h = bh & 7;
    const int q0 = blockIdx.y * 128 + wave * 32;

    const f16* kg0 = kws + (size_t)bh * MM * DH;
    const f16* vg0 = vtws + (size_t)bh * DH * MM;

    const int lrow = lane >> 3;
    const int lsw  = ((lane & 7) ^ lrow) << 4;
    const char* kP = (const char*)kg0 + (size_t)(wave * 16 + lrow) * 128 + lsw;
    const char* vP = (const char*)vg0 + (size_t)(wave * 16 + lrow) * 4096 + lsw;
    char* kD = smem + wave * 2048;
    char* vD = smem + 8192 + wave * 2048;

    gl16(kP,         kD);
    gl16(kP + 1024,  kD + 1024);
    gl16(vP,         vD);
    gl16(vP + 32768, vD + 1024);
    kP += 8192; vP += 128;

    f16x8 qf[2][2];
    const f16* qbase = qws + ((size_t)bh * NN + q0) * DH;
#pragma unroll
    for (int rt = 0; rt < 2; rt++)
#pragma unroll
        for (int ks = 0; ks < 2; ks++)
            qf[rt][ks] = *(const f16x8*)(qbase + (rt * 16 + l15) * DH + ks * 32 + quad * 8);

    int rowOk[2];
#pragma unroll
    for (int rt = 0; rt < 2; rt++)
        rowOk[rt] = mask[(size_t)b * NN + q0 + rt * 16 + l15];

    float pnull[2] = {0.0f, 0.0f};
    {
        float pn[2] = {0.f, 0.f};
#pragma unroll
        for (int ks = 0; ks < 2; ks++)
#pragma unroll
            for (int t = 0; t < 8; t++) {
                const float nkt = tanhf(nk[ks * 32 + quad * 8 + t]);
                pn[0] += (float)qf[0][ks][t] * nkt;
                pn[1] += (float)qf[1][ks][t] * nkt;
            }
#pragma unroll
        for (int rt = 0; rt < 2; rt++) {
            pn[rt] += __shfl_xor(pn[rt], 16);
            pn[rt] += __shfl_xor(pn[rt], 32);
            pnull[rt] = rowOk[rt] ? EXP2(pn[rt]) : 1.0f;
        }
    }
    float negsel[2];
#pragma unroll
    for (int rt = 0; rt < 2; rt++) {
        negsel[rt] = rowOk[rt] ? -1.0e30f : 0.0f;
        if (!rowOk[rt]) {
            const f16x8 zz = {(f16)0, (f16)0, (f16)0, (f16)0, (f16)0, (f16)0, (f16)0, (f16)0};
            qf[rt][0] = zz; qf[rt][1] = zz;
        }
    }

    f32x4 acc[2][4];
    f32x4 accl[2];
#pragma unroll
    for (int rt = 0; rt < 2; rt++)
#pragma unroll
        for (int reg = 0; reg < 4; reg++) {
            const float pr = __shfl(pnull[rt], quad * 4 + reg, 16);
            accl[rt][reg] = pr;
#pragma unroll
            for (int ds = 0; ds < 4; ds++)
                acc[rt][ds][reg] = pr * nv[ds * 16 + l15];
        }

    const f16x4 vone = {(f16)1, (f16)1, (f16)1, (f16)1};
    const int kxor = l15 & 7;

    __syncthreads();

    int buf = 0;
    for (int jc = 0; jc < MM; jc += 64) {
        int4 cmv[4];
#pragma unroll
        for (int jj = 0; jj < 4; jj++)
            cmv[jj] = *(const int4*)(cmask + (size_t)b * MM + jc + jj * 16 + quad * 4);

        if (jc + 64 < MM) {
            const int bo = (buf ^ 1) << 14;
            gl16(kP,         kD + bo);
            gl16(kP + 1024,  kD + bo + 1024);
            gl16(vP,         vD + bo);
            gl16(vP + 32768, vD + bo + 1024);
            kP += 8192; vP += 128;
        }

        const char* sKb = smem + (buf << 14);
        const char* sVb = sKb + 8192;

        f32x4 st[2][4];
#pragma unroll
        for (int rt = 0; rt < 2; rt++)
#pragma unroll
            for (int jj = 0; jj < 4; jj++) {
                st[rt][jj][0] = cmv[jj].x ? 0.0f : negsel[rt];
                st[rt][jj][1] = cmv[jj].y ? 0.0f : negsel[rt];
                st[rt][jj][2] = cmv[jj].z ? 0.0f : negsel[rt];
                st[rt][jj][3] = cmv[jj].w ? 0.0f : negsel[rt];
            }

#pragma unroll
        for (int ks = 0; ks < 2; ks++) {
            f16x8 kb[4];
#pragma unroll
            for (int jj = 0; jj < 4; jj++)
                kb[jj] = *(const f16x8*)(sKb + (jj * 16 + l15) * 128
                                             + (((ks * 4 + quad) ^ kxor) << 4));
#pragma unroll
            for (int rt = 0; rt < 2; rt++)
#pragma unroll
                for (int jj = 0; jj < 4; jj++)
                    st[rt][jj] = __builtin_amdgcn_mfma_f32_16x16x32_f16(
                        kb[jj], qf[rt][ks], st[rt][jj], 0, 0, 0);
        }

        f16x4 pa[2][4];
#pragma unroll
        for (int rt = 0; rt < 2; rt++)
#pragma unroll
            for (int jj = 0; jj < 4; jj++)
                pa[rt][jj] = pk4(EXP2(st[rt][jj][0]), EXP2(st[rt][jj][1]),
                                 EXP2(st[rt][jj][2]), EXP2(st[rt][jj][3]));

#pragma unroll
        for (int jj = 0; jj < 4; jj++) {
            f16x4 vb[4];
#pragma unroll
            for (int ds = 0; ds < 4; ds++)
                vb[ds] = *(const f16x4*)(sVb + (ds * 16 + l15) * 128
                                             + (((jj * 2 + (quad >> 1)) ^ kxor) << 4)
                                             + ((quad & 1) << 3));
#pragma unroll
            for (int rt = 0; rt < 2; rt++) {
#pragma unroll
                for (int ds = 0; ds < 4; ds++)
                    acc[rt][ds] = __builtin_amdgcn_mfma_f32_16x16x16f16(
                        pa[rt][jj], vb[ds], acc[rt][ds], 0, 0, 0);
                accl[rt] = __builtin_amdgcn_mfma_f32_16x16x16f16(
                    pa[rt][jj], vone, accl[rt], 0, 0, 0);
            }
        }

        __syncthreads();
        buf ^= 1;
    }

    // epilogue: FINAL output = acc / l  -> ofx[b][n][h*64+d]
#pragma unroll
    for (int rt = 0; rt < 2; rt++) {
        float inv[4];
#pragma unroll
        for (int reg = 0; reg < 4; reg++)
            inv[reg] = 1.0f / fmaxf(accl[rt][reg], 1e-35f);
#pragma unroll
        for (int ds = 0; ds < 4; ds++)
#pragma unroll
            for (int reg = 0; reg < 4; reg++) {
                const int r = q0 + rt * 16 + quad * 4 + reg;
                ofx[((size_t)b * 2048 + r) * 512 + h * 64 + ds * 16 + l15] =
                    (f16)(acc[rt][ds][reg] * inv[reg]);
            }
    }
}

// ---------------------------------------------------------------------------
// Final GEMM v3 (frozen): 128x64 tiles, grid (64,8) = 2 blocks/CU, gl16 DMA
// staging of A+Bh+Bl into linear dbuf LDS 2x16KB, one barrier per k-step.
// ---------------------------------------------------------------------------
__launch_bounds__(256, 4)
__global__ void mgemm2(const f16* __restrict__ A, const f16* __restrict__ Bh,
                       const f16* __restrict__ Bl,
                       float* __restrict__ o32, const float* __restrict__ bias,
                       int K)
{
    __shared__ __align__(16) char smem[32768];   // 2 x [A:8KB | Bh:4KB | Bl:4KB]

    const int tid  = threadIdx.x;
    const int wave = tid >> 6, lane = tid & 63;
    const int l15  = lane & 15, quad = lane >> 4;
    const size_t r0 = (size_t)blockIdx.x * 128;
    const int c0 = blockIdx.y * 64;

    const int blr = lane >> 2;
    const int bsw = (lane & 3) ^ ((lane >> 3) & 3);
    const char* aP = (const char*)(A + (r0 + wave * 32 + blr) * K) + bsw * 16;
    const char* hP = (const char*)(Bh + (size_t)(c0 + wave * 16 + blr) * K) + bsw * 16;
    const char* lP = (const char*)(Bl + (size_t)(c0 + wave * 16 + blr) * K) + bsw * 16;
    char* aD = smem + wave * 2048;
    char* hD = smem + 8192 + wave * 1024;
    char* lD = smem + 12288 + wave * 1024;

    gl16(aP,          aD);
    gl16(aP + 16384,  aD + 1024);   // +16 rows (16*512*2 B)
    gl16(hP,          hD);
    gl16(lP,          lD);
    aP += 64; hP += 64; lP += 64;

    const int fsw = ((quad ^ ((l15 >> 1) & 3)) << 4);
    const int aoff0 = (wave * 32 + l15) * 64 + fsw;
    const int aoff1 = aoff0 + 16 * 64;

    f32x4 acc[2][4] = {};
    __syncthreads();

    int buf = 0;
    const int NT = K / 32;
    for (int t = 0; t < NT; t++) {
        const int nb = (buf ^ 1) * 16384;
        if (t < NT - 1) {
            gl16(aP,          aD + nb);
            gl16(aP + 16384,  aD + nb + 1024);
            gl16(hP,          hD + nb);
            gl16(lP,          lD + nb);
            aP += 64; hP += 64; lP += 64;
        }
        const char* sA = smem + buf * 16384;
        const char* sH = sA + 8192;
        const char* sL = sA + 12288;

        f16x8 a[2];
        a[0] = *(const f16x8*)(sA + aoff0);
        a[1] = *(const f16x8*)(sA + aoff1);
#pragma unroll
        for (int ct = 0; ct < 4; ct++) {
            const int boff = (ct * 16 + l15) * 64 + fsw;
            f16x8 bh = *(const f16x8*)(sH + boff);
            f16x8 bl = *(const f16x8*)(sL + boff);
#pragma unroll
            for (int rt = 0; rt < 2; rt++) {
                acc[rt][ct] = __builtin_amdgcn_mfma_f32_16x16x32_f16(
                    a[rt], bh, acc[rt][ct], 0, 0, 0);
                acc[rt][ct] = __builtin_amdgcn_mfma_f32_16x16x32_f16(
                    a[rt], bl, acc[rt][ct], 0, 0, 0);
            }
        }
        __syncthreads();
        buf ^= 1;
    }

#pragma unroll
    for (int rt = 0; rt < 2; rt++)
#pragma unroll
        for (int ct = 0; ct < 4; ct++) {
            const int col = c0 + ct * 16 + l15;
            const float bv = bias[col];
#pragma unroll
            for (int reg = 0; reg < 4; reg++) {
                const size_t row = r0 + wave * 32 + rt * 16 + quad * 4 + reg;
                o32[row * 512 + col] = acc[rt][ct][reg] + bv;
            }
        }
}

extern "C" void kernel_launch(void* const* d_in, const int* in_sizes, int n_in,
                              void* d_out, int out_size, void* d_ws, size_t ws_size,
                              hipStream_t stream)
{
    const float* x    = (const float*)d_in[0];
    const float* ctx  = (const float*)d_in[1];
    const int*   mask = (const int*)d_in[2];
    const int*   cmsk = (const int*)d_in[3];
    const float* Wq   = (const float*)d_in[4];
    const float* Wkv  = (const float*)d_in[5];
    const float* Wo   = (const float*)d_in[6];
    const float* bo   = (const float*)d_in[7];
    const float* nk   = (const float*)d_in[8];
    const float* nv   = (const float*)d_in[9];
    float* out = (float*)d_out;

    const size_t S = (size_t)BB * HEADS * NN * DH;  // 4,194,304 elems

    f16* qws = (f16*)d_ws;                  // 8 MB
    f16* kws = qws + S;                     // 8 MB
    f16* vt  = kws + S;                     // 8 MB
    f16* wq16  = vt + S;                    // 0.5 MB
    f16* wkv16 = wq16 + 512 * 512;          // 1 MB
    f16* woh = wkv16 + 512 * 1024;          // 0.5 MB
    f16* wol = woh + 512 * 512;             // 0.5 MB
    float* lp = (float*)(wol + 512 * 512);  // 1 MB (unused)
    f16* ofx = (f16*)(lp + 4 * 32 * 2048);  // final attn output, 8 MB

    wprep_k<<<512, 256, 0, stream>>>(Wq, Wkv, Wo, wq16, wkv16, woh, wol);
    proj_k<<<dim3(64, 12), 256, 0, stream>>>(x, ctx, wq16, wkv16, qws, kws, vt);
    attn_k<<<dim3(32, 16), 256, 0, stream>>>(qws, kws, vt, mask, cmsk, nk, nv, ofx);
    mgemm2<<<dim3(64, 8), 256, 0, stream>>>(ofx, woh, wol, out, bo, 512);
}